// Round 5
// baseline (150.839 us; speedup 1.0000x reference)
//
#include <hip/hip_runtime.h>

#define W 512
#define PLANE (W * W)            // 262144
#define NPTS (32 * PLANE)        // 8388608 spatial points per channel
#define ROWS 8                   // compute rows per block
#define STRIP (ROWS + 2)         // staged rows (y halo) = 10
#define HC 256                   // columns per block (half row)
#define NBLK 4096                // 32 batches * 64 strips * 2 halves

static constexpr float DT_INV = 100.0f;   // 1/DT
static constexpr float NU_C   = 0.001f;
// DX = 1.0 -> grad scale 0.5, laplacian scale 1.0

// v9: occupancy-doubling experiment on the best-measured structure (v5).
// Same global_load_lds DMA staging (compiler-proof in-flight loads: they
// live in the vmcnt queue, not registers, so the scheduler cannot sink
// them — v8 showed plain-load pipelines get collapsed at VGPR=56).
// Tile shrunk to 8 rows x 256 cols: LDS = 2ch*10*256*4 = 20480 B exactly
// -> 8 blocks/CU (160 KiB / 20 KB), 32 waves/CU = 2x v5's residency.
// Logical traffic identical to v5 (halo ratio 10/8). x-edges outside the
// 256-col tile come from 4 broadcast scalar loads per thread-row.
// Discriminates: concurrency-capped (expect ~30 us) vs hard ~3.6 TB/s
// service ceiling (expect ~43 us at doubled occupancy).
__global__ __launch_bounds__(256, 8) void ns_loss_v9(
    const float* __restrict__ u_pred,
    const float* __restrict__ u_prev,
    float* __restrict__ partial)
{
    __shared__ float smem[2 * STRIP * HC];  // u strip | v strip, 20480 B

    const int t    = threadIdx.x;
    const int lane = t & 63;
    const int wv   = t >> 6;

    // bijective XCD swizzle (4096 % 8 == 0): each XCD gets 512 consecutive
    // lids = 4 whole batches; adjacent segments/halves stay on one L2.
    const int bid = blockIdx.x;
    const int lid = ((bid & 7) << 9) | (bid >> 3);

    const int b    = lid >> 7;              // 0..31
    const int rem  = lid & 127;
    const int y0   = (rem >> 1) << 3;       // strip base row
    const int cb   = (rem & 1) << 8;        // column-half base (0 or 256)

    const float* u0 = u_pred + (size_t)b * (2 * PLANE);
    const float* v0 = u0 + PLANE;
    const float* q0 = u_prev + (size_t)b * (2 * PLANE);
    const float* q1 = q0 + PLANE;

    // ---- async DMA staging: 20 segments of 1024 B (256-col half-rows) ----
    // segment s: channel = s>=10, strip-row r = s%10
#pragma unroll
    for (int k = 0; k < 5; ++k) {
        const int s  = wv * 5 + k;
        const int ch = s >= 10 ? 1 : 0;
        const int r  = s - 10 * ch;
        const int grow = (y0 - 1 + r) & 511;
        const float* gsrc = (ch ? v0 : u0) + grow * W + cb + lane * 4;
        float* ldst = smem + ch * (STRIP * HC) + r * HC;   // wave-uniform base
        __builtin_amdgcn_global_load_lds(
            (const __attribute__((address_space(1))) void*)gsrc,
            (__attribute__((address_space(3))) void*)ldst, 16, 0, 0);
    }

    // ---- overlap DMA: prev center quads + x-edge scalars to registers ----
    const int rr = t >> 5;                  // tile row 0..7
    const int j  = t & 31;                  // lane within row group
    const int yg = y0 + rr;                 // global row (<=511, no wrap)
    const int rowg = yg * W;
    const int cLg = (cb + 511) & 511;       // global col left of tile
    const int cRg = (cb + 256) & 511;       // global col right of tile

    float4 pu[2], pv[2];
#pragma unroll
    for (int g = 0; g < 2; ++g) {
        const int x = cb + (j << 2) + (g << 7);
        pu[g] = *(const float4*)(q0 + rowg + x);
        pv[g] = *(const float4*)(q1 + rowg + x);
    }
    const float uL_e = u0[rowg + cLg];
    const float uR_e = u0[rowg + cRg];
    const float vL_e = v0[rowg + cLg];
    const float vR_e = v0[rowg + cRg];

    __syncthreads();   // drains DMA (vmcnt) + barrier

    // ---- stencil from LDS ----
    const float* us = smem;
    const float* vs = smem + STRIP * HC;
    const int rc = rr + 1;                  // center row inside strip

    float4 uc[2], vc[2];
#pragma unroll
    for (int g = 0; g < 2; ++g) {
        const int x = (j << 2) + (g << 7);
        uc[g] = *(const float4*)(us + rc * HC + x);
        vc[g] = *(const float4*)(vs + rc * HC + x);
    }

    // x-neighbor edges via width-32 shuffles (row group = 32 lanes)
    float uLs[2], uRs[2], vLs[2], vRs[2];
#pragma unroll
    for (int g = 0; g < 2; ++g) {
        uLs[g] = __shfl(uc[g].w, (j + 31) & 31, 32);
        uRs[g] = __shfl(uc[g].x, (j + 1) & 31, 32);
        vLs[g] = __shfl(vc[g].w, (j + 31) & 31, 32);
        vRs[g] = __shfl(vc[g].x, (j + 1) & 31, 32);
    }

    float s_pde = 0.0f, s_div = 0.0f;
#pragma unroll
    for (int g = 0; g < 2; ++g) {
        const int x = (j << 2) + (g << 7);
        const float4 um = *(const float4*)(us + (rc - 1) * HC + x);
        const float4 up = *(const float4*)(us + (rc + 1) * HC + x);
        const float4 vm = *(const float4*)(vs + (rc - 1) * HC + x);
        const float4 vp = *(const float4*)(vs + (rc + 1) * HC + x);

        // quad 0 lane 0's left neighbor and quad 1 lane 31's right neighbor
        // live outside the tile (global scalars); the inter-quad seam
        // (cols cb+127/cb+128) is covered by the cross-quad shuffle picks.
        const float uL = (j == 0)  ? (g == 0 ? uL_e : uLs[0]) : uLs[g];
        const float uR = (j == 31) ? (g == 1 ? uR_e : uRs[1]) : uRs[g];
        const float vL = (j == 0)  ? (g == 0 ? vL_e : vLs[0]) : vLs[g];
        const float vR = (j == 31) ? (g == 1 ? vR_e : vRs[1]) : vRs[g];

        const float ua[6]  = {uL, uc[g].x, uc[g].y, uc[g].z, uc[g].w, uR};
        const float va[6]  = {vL, vc[g].x, vc[g].y, vc[g].z, vc[g].w, vR};
        const float umA[4] = {um.x, um.y, um.z, um.w};
        const float upA[4] = {up.x, up.y, up.z, up.w};
        const float vmA[4] = {vm.x, vm.y, vm.z, vm.w};
        const float vpA[4] = {vp.x, vp.y, vp.z, vp.w};
        const float puA[4] = {pu[g].x, pu[g].y, pu[g].z, pu[g].w};
        const float pvA[4] = {pv[g].x, pv[g].y, pv[g].z, pv[g].w};

#pragma unroll
        for (int q = 0; q < 4; ++q) {
            const float u   = ua[q + 1];
            const float v   = va[q + 1];
            const float u_x = (ua[q + 2] - ua[q]) * 0.5f;
            const float v_x = (va[q + 2] - va[q]) * 0.5f;
            const float u_y = (upA[q] - umA[q]) * 0.5f;
            const float v_y = (vpA[q] - vmA[q]) * 0.5f;
            const float lap_u = upA[q] + umA[q] + ua[q + 2] + ua[q] - 4.0f * u;
            const float lap_v = vpA[q] + vmA[q] + va[q + 2] + va[q] - 4.0f * v;
            const float rx = (u - puA[q]) * DT_INV + u * u_x + v * u_y - NU_C * lap_u;
            const float ry = (v - pvA[q]) * DT_INV + u * v_x + v * v_y - NU_C * lap_v;
            const float dv = u_x + v_y;
            s_pde += rx * rx + ry * ry;
            s_div += dv * dv;
        }
    }

    // ---- reduction ----
#pragma unroll
    for (int off = 32; off > 0; off >>= 1) {
        s_pde += __shfl_down(s_pde, off);
        s_div += __shfl_down(s_div, off);
    }

    __syncthreads();   // all LDS stencil reads done; safe to reuse smem
    if (lane == 0) { smem[wv] = s_pde; smem[8 + wv] = s_div; }
    __syncthreads();
    if (t == 0) {
        partial[lid]        = smem[0] + smem[1] + smem[2] + smem[3];
        partial[NBLK + lid] = smem[8] + smem[9] + smem[10] + smem[11];
    }
}

__global__ __launch_bounds__(256) void ns_reduce(
    const float* __restrict__ partial,
    float* __restrict__ out)
{
    double sp = 0.0, sd = 0.0;
    for (int i = threadIdx.x; i < NBLK; i += 256) {
        sp += (double)partial[i];
        sd += (double)partial[NBLK + i];
    }
#pragma unroll
    for (int off = 32; off > 0; off >>= 1) {
        sp += __shfl_down(sp, off);
        sd += __shfl_down(sd, off);
    }
    __shared__ double ssp[4], ssd[4];
    const int lane = threadIdx.x & 63;
    const int wv   = threadIdx.x >> 6;
    if (lane == 0) { ssp[wv] = sp; ssd[wv] = sd; }
    __syncthreads();
    if (threadIdx.x == 0) {
        const double tp = ssp[0] + ssp[1] + ssp[2] + ssp[3];
        const double td = ssd[0] + ssd[1] + ssd[2] + ssd[3];
        const double inv = 1.0 / (double)NPTS;
        const double pde = tp * inv;
        const double dvl = td * inv;
        out[0] = (float)(pde + 0.1 * dvl);
        out[1] = (float)pde;
        out[2] = (float)dvl;
    }
}

extern "C" void kernel_launch(void* const* d_in, const int* in_sizes, int n_in,
                              void* d_out, int out_size, void* d_ws, size_t ws_size,
                              hipStream_t stream) {
    const float* u_pred = (const float*)d_in[0];
    const float* u_prev = (const float*)d_in[1];
    float* out = (float*)d_out;
    float* partial = (float*)d_ws;   // 2*NBLK floats = 32 KB

    ns_loss_v9<<<NBLK, 256, 0, stream>>>(u_pred, u_prev, partial);
    ns_reduce<<<1, 256, 0, stream>>>(partial, out);
}